// Round 4
// baseline (393.369 us; speedup 1.0000x reference)
//
#include <hip/hip_runtime.h>
#include <hip/hip_bf16.h>
#include <math.h>

// LinearAttention, bf16-MFMA pipeline, fused output stage.
// dims: B=16, C=256, H=W=64 (n=4096), HEADS=8, dh=32, HID=256, 3*HID=768.
//
// ws layout (bytes):
//   qkv_bf  @ 0          : 16*768*4096*2 = 100,663,296   (bf16)
//   xt      @ 100663296  : 16*4096*256*2 =  33,554,432   (bf16, [b][p][c])
//   wbf     @ 134217728  : (768*256 + 256*256)*2 = 524,288 (w_qkv_bf ++ w_out_bf)
//   kmax    @ 134742016  : 4096*4
//   krecip  @ 134758400  : 4096*4
//   part    @ 134774784  : 128*8*1024*4 = 4,194,304
//   ctxb    @ 138969088  : 128*1024*2   = 262,144        (bf16, [bh][e][d])

typedef __attribute__((ext_vector_type(8))) short bf16x8;
typedef __attribute__((ext_vector_type(4))) float f32x4;
typedef __attribute__((ext_vector_type(8))) unsigned short u16x8;

#define GL16(g, l) __builtin_amdgcn_global_load_lds( \
    (__attribute__((address_space(1))) void*)(void*)(g), \
    (__attribute__((address_space(3))) void*)(void*)(l), 16, 0, 0)

__device__ inline float b2f(unsigned short u) {
    union { float f; unsigned int i; } v; v.i = ((unsigned int)u) << 16; return v.f;
}
__device__ inline unsigned short f2b(float f) {
    union { float f; unsigned int i; } v; v.f = f;
    unsigned int r = v.i + 0x7fff + ((v.i >> 16) & 1);   // round-nearest-even
    return (unsigned short)(r >> 16);
}

// ---------------- K0w: weights fp32 -> bf16 (w_qkv then w_out, one arena) ----
__global__ __launch_bounds__(256) void conv_w(
    const float* __restrict__ wq, const float* __restrict__ wo,
    unsigned short* __restrict__ dst)
{
    int i4 = (blockIdx.x * 256 + threadIdx.x) * 4;   // 0..262140
    float4 v = (i4 < 196608) ? *(const float4*)&wq[i4]
                             : *(const float4*)&wo[i4 - 196608];
    unsigned int lo = (unsigned int)f2b(v.x) | ((unsigned int)f2b(v.y) << 16);
    unsigned int hi = (unsigned int)f2b(v.z) | ((unsigned int)f2b(v.w) << 16);
    *(uint2*)&dst[i4] = make_uint2(lo, hi);
}

// ---------------- K0x: x[b][c][p] fp32 -> xt[b][p][c] bf16 (tiled transpose) --
__global__ __launch_bounds__(256) void conv_x(
    const float* __restrict__ x, unsigned short* __restrict__ xt)
{
    __shared__ __align__(16) unsigned short T[64][72];
    const int t = threadIdx.x;
    const int p0 = blockIdx.x * 64, c0 = blockIdx.y * 64, b = blockIdx.z;
    const float* xb = x + ((size_t)b * 256 + c0) * 4096 + p0;
    #pragma unroll
    for (int i = 0; i < 4; ++i) {
        int flat = i * 256 + t;
        int cl = flat >> 4, p4 = (flat & 15) * 4;
        float4 v = *(const float4*)&xb[(size_t)cl * 4096 + p4];
        T[p4 + 0][cl] = f2b(v.x);
        T[p4 + 1][cl] = f2b(v.y);
        T[p4 + 2][cl] = f2b(v.z);
        T[p4 + 3][cl] = f2b(v.w);
    }
    __syncthreads();
    unsigned short* xtb = xt + ((size_t)b * 4096 + p0) * 256 + c0;
    #pragma unroll
    for (int j = 0; j < 2; ++j) {
        int flat = j * 256 + t;
        int row = flat >> 3, ch = flat & 7;
        uint4 v = *(const uint4*)&T[row][ch * 8];
        *(uint4*)&xtb[(size_t)row * 256 + ch * 8] = v;
    }
}

// ---------------- K1: qkv[b][o][p] = sum_c Wq[o][c] * X[b][c][p], bf16 MFMA ---
__global__ __launch_bounds__(256) void qkv_mfma(
    const unsigned short* __restrict__ wq,   // [768][256] bf16
    const unsigned short* __restrict__ xt,   // [b][4096][256] bf16
    unsigned short* __restrict__ qkv)        // [b][768][4096] bf16
{
    __shared__ __align__(16) unsigned short As[128 * 64];   // 16 KB
    __shared__ __align__(16) unsigned short Bs[128 * 64];   // 16 KB
    const int t = threadIdx.x;
    const int l = t & 63, w = t >> 6;
    const int lm = l & 15, kg = l >> 4, le = l & 7, l3 = l >> 3;
    const int sx8 = (le ^ l3) * 8;          // source chunk (ushort units)
    const int p0 = blockIdx.x * 128, o0 = blockIdx.y * 128, b = blockIdx.z;
    const int wo = (w >> 1) * 64, wp = (w & 1) * 64;

    f32x4 acc[4][4] = {};
    const unsigned short* xb = xt + (size_t)b * 4096 * 256;

    for (int ks = 0; ks < 4; ++ks) {
        const int e0 = ks * 64;
        #pragma unroll
        for (int i = 0; i < 4; ++i) {
            int cid = w * 4 + i;            // 0..15, covers rows cid*8..+8
            int m = cid * 8 + l3;
            GL16(wq + (size_t)(o0 + m) * 256 + e0 + sx8, &As[cid * 512]);
            GL16(xb + (size_t)(p0 + m) * 256 + e0 + sx8, &Bs[cid * 512]);
        }
        __syncthreads();
        #pragma unroll
        for (int s = 0; s < 2; ++s) {
            bf16x8 af[4], bfr[4];
            #pragma unroll
            for (int mi = 0; mi < 4; ++mi) {
                int row = wo + mi * 16 + lm;
                int ch = ((s * 4 + kg) ^ (row & 7)) * 8;
                af[mi] = *(const bf16x8*)&As[row * 64 + ch];
            }
            #pragma unroll
            for (int ni = 0; ni < 4; ++ni) {
                int row = wp + ni * 16 + lm;
                int ch = ((s * 4 + kg) ^ (row & 7)) * 8;
                bfr[ni] = *(const bf16x8*)&Bs[row * 64 + ch];
            }
            #pragma unroll
            for (int mi = 0; mi < 4; ++mi)
                #pragma unroll
                for (int ni = 0; ni < 4; ++ni)
                    acc[mi][ni] = __builtin_amdgcn_mfma_f32_16x16x32_bf16(
                        af[mi], bfr[ni], acc[mi][ni], 0, 0, 0);
        }
        __syncthreads();
    }
    unsigned short* ob = qkv + (size_t)b * 768 * 4096;
    #pragma unroll
    for (int mi = 0; mi < 4; ++mi)
        #pragma unroll
        for (int ni = 0; ni < 4; ++ni) {
            int o = o0 + wo + mi * 16 + kg * 4;
            int p = p0 + wp + ni * 16 + lm;
            #pragma unroll
            for (int r = 0; r < 4; ++r)
                ob[(size_t)(o + r) * 4096 + p] = f2b(acc[mi][ni][r]);
        }
}

// ---------------- K2: k-softmax row stats (bf16 in) --------------------------
__global__ __launch_bounds__(256) void kstats(
    const unsigned short* __restrict__ qkv,
    float* __restrict__ kmax, float* __restrict__ krecip)
{
    const int row = blockIdx.x;              // b*256 + cd
    const int b = row >> 8, cd = row & 255;
    const int t = threadIdx.x;
    const unsigned short* kp = qkv + ((size_t)b * 768 + 256 + cd) * 4096 + t * 16;
    float v[16]; float m = -1e30f;
    u16x8 a0 = *(const u16x8*)kp;
    u16x8 a1 = *(const u16x8*)(kp + 8);
    #pragma unroll
    for (int i = 0; i < 8; ++i) { v[i] = b2f(a0[i]); v[8 + i] = b2f(a1[i]); }
    #pragma unroll
    for (int i = 0; i < 16; ++i) m = fmaxf(m, v[i]);
    #pragma unroll
    for (int off = 32; off > 0; off >>= 1) m = fmaxf(m, __shfl_xor(m, off));
    __shared__ float red[8];
    if ((t & 63) == 0) red[t >> 6] = m;
    __syncthreads();
    m = fmaxf(fmaxf(red[0], red[1]), fmaxf(red[2], red[3]));
    float s = 0.f;
    #pragma unroll
    for (int i = 0; i < 16; ++i) s += __expf(v[i] - m);
    #pragma unroll
    for (int off = 32; off > 0; off >>= 1) s += __shfl_xor(s, off);
    __syncthreads();
    if ((t & 63) == 0) red[4 + (t >> 6)] = s;
    __syncthreads();
    if (t == 0) {
        float S = red[4] + red[5] + red[6] + red[7];
        kmax[row] = m;
        krecip[row] = 1.0f / (S * 4096.0f);   // folds v/n
    }
}

// ---------------- K3: context partials (bf16 in) -----------------------------
__global__ __launch_bounds__(256) void ctx_partial(
    const unsigned short* __restrict__ qkv,
    const float* __restrict__ kmax, const float* __restrict__ krecip,
    float* __restrict__ part)
{
    const int seg = blockIdx.x, bh = blockIdx.y;
    const int b = bh >> 3, h = bh & 7;
    const int t = threadIdx.x;
    __shared__ float kc[32][65];
    __shared__ __align__(16) float vt[64][36];
    const unsigned short* kb = qkv + ((size_t)b * 768 + 256 + h * 32) * 4096;
    const unsigned short* vb = qkv + ((size_t)b * 768 + 512 + h * 32) * 4096;
    const int d = t >> 3, e0 = (t & 7) * 4;
    float a0 = 0, a1 = 0, a2 = 0, a3 = 0;

    for (int ch = 0; ch < 8; ++ch) {
        const int pb = seg * 512 + ch * 64;
        #pragma unroll
        for (int r = 0; r < 4; ++r) {
            int dd = r * 8 + (t >> 5);
            int pp = (t & 31) * 2;
            unsigned int kraw = *(const unsigned int*)&kb[(size_t)dd * 4096 + pb + pp];
            float mx = kmax[bh * 32 + dd], rc = krecip[bh * 32 + dd];
            kc[dd][pp]     = __expf(b2f((unsigned short)(kraw & 0xffff)) - mx) * rc;
            kc[dd][pp + 1] = __expf(b2f((unsigned short)(kraw >> 16)) - mx) * rc;
            unsigned int vraw = *(const unsigned int*)&vb[(size_t)dd * 4096 + pb + pp];
            vt[pp][dd]     = b2f((unsigned short)(vraw & 0xffff));
            vt[pp + 1][dd] = b2f((unsigned short)(vraw >> 16));
        }
        __syncthreads();
        #pragma unroll
        for (int pp = 0; pp < 64; ++pp) {
            float kd = kc[d][pp];
            float4 v4 = *(const float4*)&vt[pp][e0];
            a0 += kd * v4.x; a1 += kd * v4.y; a2 += kd * v4.z; a3 += kd * v4.w;
        }
        __syncthreads();
    }
    float* pp = part + ((size_t)(bh * 8 + seg) * 32 + d) * 32 + e0;
    pp[0] = a0; pp[1] = a1; pp[2] = a2; pp[3] = a3;
}

// ---------------- K3b: reduce partials -> ctxb bf16 [bh][e][d] ---------------
__global__ __launch_bounds__(256) void ctx_reduce(
    const float* __restrict__ part, unsigned short* __restrict__ ctxb)
{
    const int bh = blockIdx.x; const int t = threadIdx.x;
    #pragma unroll
    for (int r = 0; r < 4; ++r) {
        int oi = r * 256 + t;            // = e*32 + d
        int e = oi >> 5, d = oi & 31;
        float s = 0.f;
        #pragma unroll
        for (int sg = 0; sg < 8; ++sg) s += part[((size_t)bh * 8 + sg) * 1024 + d * 32 + e];
        ctxb[(size_t)bh * 1024 + oi] = f2b(s);
    }
}

// ---------------- K4: fused q-softmax + ctx + out-proj + LayerNorm (MFMA) ----
// Block: 64 pixels x one batch. Wave w owns pixel rows wp=w*16..+16.
// LDS union: qT/out bf16 [64][260] -> Wout chunk bf16 [256][36] -> fbuf f32 [128][68]
#define RS 260
__global__ __launch_bounds__(256) void attn_out(
    const unsigned short* __restrict__ qkv,    // q part: [b][0..256][4096]
    const unsigned short* __restrict__ ctxb,   // [bh][e][d] bf16
    const unsigned short* __restrict__ woutb,  // [256 c][256 e] bf16
    const float* __restrict__ b_out, const float* __restrict__ g,
    float* __restrict__ y)
{
    __shared__ __align__(16) unsigned char smem[34816];
    unsigned short* qT  = (unsigned short*)smem;   // [64][RS]
    unsigned short* wch = (unsigned short*)smem;   // [256][36]
    float*          fb  = (float*)smem;            // [128][68]

    const int t = threadIdx.x, l = t & 63, w = t >> 6;
    const int lm = l & 15, kg = l >> 4;
    const int p0 = blockIdx.x * 64, b = blockIdx.y;
    const int wp = w * 16;

    // ---- stage qT[p][o] from q[o][p0..+64] (scalar transpose) ----
    const unsigned short* qb = qkv + (size_t)b * 768 * 4096 + p0;
    #pragma unroll
    for (int i = 0; i < 8; ++i) {
        int flat = i * 256 + t;          // 0..2047
        int o = flat >> 3, j = flat & 7;
        u16x8 v = *(const u16x8*)&qb[(size_t)o * 4096 + j * 8];
        #pragma unroll
        for (int s = 0; s < 8; ++s) qT[(j * 8 + s) * RS + o] = (unsigned short)v[s];
    }
    __syncthreads();

    // ---- phase A: per-head q-softmax (A-frag) -> MFMA with ctx -> out in qT ----
    const float scale = 0.17677669529663689f;   // dh^-0.5
    #pragma unroll
    for (int h = 0; h < 8; ++h) {
        bf16x8 araw = *(const bf16x8*)&qT[(wp + lm) * RS + h * 32 + kg * 8];
        float ex[8]; float m = -1e30f;
        #pragma unroll
        for (int i = 0; i < 8; ++i) { ex[i] = b2f((unsigned short)araw[i]); m = fmaxf(m, ex[i]); }
        m = fmaxf(m, __shfl_xor(m, 16)); m = fmaxf(m, __shfl_xor(m, 32));
        float s = 0.f;
        #pragma unroll
        for (int i = 0; i < 8; ++i) { ex[i] = __expf(ex[i] - m); s += ex[i]; }
        s += __shfl_xor(s, 16); s += __shfl_xor(s, 32);
        const float inv = scale / s;
        bf16x8 a1;
        #pragma unroll
        for (int i = 0; i < 8; ++i) a1[i] = (short)f2b(ex[i] * inv);
        const unsigned short* cb = ctxb + ((size_t)(b * 8 + h)) * 1024;
        bf16x8 b1a = *(const bf16x8*)&cb[lm * 32 + kg * 8];
        bf16x8 b1b = *(const bf16x8*)&cb[(16 + lm) * 32 + kg * 8];
        f32x4 c0 = {0.f, 0.f, 0.f, 0.f}, c1 = {0.f, 0.f, 0.f, 0.f};
        c0 = __builtin_amdgcn_mfma_f32_16x16x32_bf16(a1, b1a, c0, 0, 0, 0);
        c1 = __builtin_amdgcn_mfma_f32_16x16x32_bf16(a1, b1b, c1, 0, 0, 0);
        #pragma unroll
        for (int r = 0; r < 4; ++r) {
            int p = wp + kg * 4 + r;
            qT[p * RS + h * 32 + lm]      = f2b(c0[r]);
            qT[p * RS + h * 32 + 16 + lm] = f2b(c1[r]);
        }
    }
    // hoist A2 fragments (wave-local rows; LDS same-wave ops are in-order)
    bf16x8 a2[8];
    #pragma unroll
    for (int kc = 0; kc < 8; ++kc)
        a2[kc] = *(const bf16x8*)&qT[(wp + lm) * RS + kc * 32 + kg * 8];

    // ---- phase B: y = Wout * out (K=256), Wout staged in LDS chunks ----
    f32x4 c2[16];
    #pragma unroll
    for (int ct = 0; ct < 16; ++ct) c2[ct] = (f32x4){0.f, 0.f, 0.f, 0.f};
    for (int kc = 0; kc < 8; ++kc) {
        __syncthreads();   // prev chunk reads done (first iter: A2 hoist done)
        #pragma unroll
        for (int i = 0; i < 4; ++i) {
            int flat = i * 256 + t;      // 0..1023
            int c = flat >> 2, j = flat & 3;
            u16x8 v = *(const u16x8*)&woutb[(size_t)c * 256 + kc * 32 + j * 8];
            *(u16x8*)&wch[c * 36 + j * 8] = v;
        }
        __syncthreads();
        #pragma unroll
        for (int ct = 0; ct < 16; ++ct) {
            bf16x8 b2 = *(const bf16x8*)&wch[(ct * 16 + lm) * 36 + kg * 8];
            c2[ct] = __builtin_amdgcn_mfma_f32_16x16x32_bf16(a2[kc], b2, c2[ct], 0, 0, 0);
        }
    }

    // ---- epilogue: bias + LayerNorm (in-register) ----
    float bias[16], gam[16];
    #pragma unroll
    for (int ct = 0; ct < 16; ++ct) { bias[ct] = b_out[ct * 16 + lm]; gam[ct] = g[ct * 16 + lm]; }
    float s1[4] = {0.f, 0.f, 0.f, 0.f}, s2[4] = {0.f, 0.f, 0.f, 0.f};
    #pragma unroll
    for (int ct = 0; ct < 16; ++ct)
        #pragma unroll
        for (int r = 0; r < 4; ++r) {
            float v = c2[ct][r] + bias[ct];
            c2[ct][r] = v; s1[r] += v; s2[r] += v * v;
        }
    #pragma unroll
    for (int off = 1; off < 16; off <<= 1) {
        #pragma unroll
        for (int r = 0; r < 4; ++r) { s1[r] += __shfl_xor(s1[r], off); s2[r] += __shfl_xor(s2[r], off); }
    }
    float mn[4], rsd[4];
    #pragma unroll
    for (int r = 0; r < 4; ++r) {
        mn[r] = s1[r] * (1.f / 256.f);
        float var = s2[r] * (1.f / 256.f) - mn[r] * mn[r];
        rsd[r] = rsqrtf(var + 1e-5f);
    }

    // ---- store via LDS transpose, 2 passes of 128 c, coalesced fp32 writes ----
    float* ybase = y + (size_t)b * 256 * 4096 + p0;
    for (int pass = 0; pass < 2; ++pass) {
        __syncthreads();   // LDS free (phase B reads / prev pass reads done)
        #pragma unroll
        for (int ct8 = 0; ct8 < 8; ++ct8) {
            int ct = pass * 8 + ct8;
            int row = ct8 * 16 + lm;
            int chunk = (wp >> 2) + kg;                 // col/4 = p/4 within 64
            int chs = (chunk ^ (row & 7)) * 4;          // swizzled col base
            #pragma unroll
            for (int r = 0; r < 4; ++r)
                fb[row * 68 + chs + r] = (c2[ct][r] - mn[r]) * rsd[r] * gam[ct];
        }
        __syncthreads();
        {
            int row = t >> 1, half = t & 1;             // 128 rows, 2 threads/row
            int cg = pass * 128 + row;
            #pragma unroll
            for (int j = 0; j < 8; ++j) {
                int chunk = (half * 8 + j) ^ (row & 7);
                float4 v = *(const float4*)&fb[row * 68 + chunk * 4];
                *(float4*)&ybase[(size_t)cg * 4096 + half * 32 + j * 4] = v;
            }
        }
    }
}

extern "C" void kernel_launch(void* const* d_in, const int* in_sizes, int n_in,
                              void* d_out, int out_size, void* d_ws, size_t ws_size,
                              hipStream_t stream) {
    const float* x     = (const float*)d_in[0];
    const float* w_qkv = (const float*)d_in[1];
    const float* w_out = (const float*)d_in[2];
    const float* b_out = (const float*)d_in[3];
    const float* g     = (const float*)d_in[4];
    float* y = (float*)d_out;

    char* ws = (char*)d_ws;
    unsigned short* qkvb  = (unsigned short*)ws;                    // 100,663,296
    unsigned short* xt    = (unsigned short*)(ws + 100663296);      //  33,554,432
    unsigned short* wbf   = (unsigned short*)(ws + 134217728);      //     524,288
    float*          kmax  = (float*)(ws + 134742016);               //      16,384
    float*          krec  = (float*)(ws + 134758400);               //      16,384
    float*          part  = (float*)(ws + 134774784);               //   4,194,304
    unsigned short* ctxb  = (unsigned short*)(ws + 138969088);      //     262,144

    conv_w<<<256, 256, 0, stream>>>(w_qkv, w_out, wbf);
    conv_x<<<dim3(64, 4, 16), 256, 0, stream>>>(x, xt);
    qkv_mfma<<<dim3(32, 6, 16), 256, 0, stream>>>(wbf, xt, qkvb);
    kstats<<<4096, 256, 0, stream>>>(qkvb, kmax, krec);
    ctx_partial<<<dim3(8, 128), 256, 0, stream>>>(qkvb, kmax, krec, part);
    ctx_reduce<<<128, 256, 0, stream>>>(part, ctxb);
    attn_out<<<dim3(64, 16), 256, 0, stream>>>(qkvb, ctxb, wbf + 196608, b_out, g, y);
}

// Round 5
// 336.988 us; speedup vs baseline: 1.1673x; 1.1673x over previous
//
#include <hip/hip_runtime.h>
#include <hip/hip_bf16.h>
#include <math.h>

// LinearAttention, bf16-MFMA pipeline, barrier-free fused output stage.
// dims: B=16, C=256, H=W=64 (n=4096), HEADS=8, dh=32, HID=256, 3*HID=768.
//
// ws layout (bytes):
//   qkv_bf  @ 0          : 16*768*4096*2 = 100,663,296   (bf16)
//   xt      @ 100663296  : 16*4096*256*2 =  33,554,432   (bf16, [b][p][c])
//   wbf     @ 134217728  : (768*256 + 256*256)*2 = 524,288 (w_qkv_bf ++ w_out_bf)
//   kmax    @ 134742016  : 4096*4
//   krecip  @ 134758400  : 4096*4
//   part    @ 134774784  : 128*8*1024*4 = 4,194,304
//   ctxb    @ 138969088  : 128*1024*2   = 262,144        (bf16, [bh][e][d])

typedef __attribute__((ext_vector_type(8))) short bf16x8;
typedef __attribute__((ext_vector_type(4))) float f32x4;
typedef __attribute__((ext_vector_type(8))) unsigned short u16x8;

#define GL16(g, l) __builtin_amdgcn_global_load_lds( \
    (__attribute__((address_space(1))) void*)(void*)(g), \
    (__attribute__((address_space(3))) void*)(void*)(l), 16, 0, 0)

__device__ inline float b2f(unsigned short u) {
    union { float f; unsigned int i; } v; v.i = ((unsigned int)u) << 16; return v.f;
}
__device__ inline unsigned short f2b(float f) {
    union { float f; unsigned int i; } v; v.f = f;
    unsigned int r = v.i + 0x7fff + ((v.i >> 16) & 1);   // round-nearest-even
    return (unsigned short)(r >> 16);
}

// ---------------- K0w: weights fp32 -> bf16 (w_qkv then w_out, one arena) ----
__global__ __launch_bounds__(256) void conv_w(
    const float* __restrict__ wq, const float* __restrict__ wo,
    unsigned short* __restrict__ dst)
{
    int i4 = (blockIdx.x * 256 + threadIdx.x) * 4;   // 0..262140
    float4 v = (i4 < 196608) ? *(const float4*)&wq[i4]
                             : *(const float4*)&wo[i4 - 196608];
    unsigned int lo = (unsigned int)f2b(v.x) | ((unsigned int)f2b(v.y) << 16);
    unsigned int hi = (unsigned int)f2b(v.z) | ((unsigned int)f2b(v.w) << 16);
    *(uint2*)&dst[i4] = make_uint2(lo, hi);
}

// ---------------- K0x: x[b][c][p] fp32 -> xt[b][p][c] bf16 (tiled transpose) --
__global__ __launch_bounds__(256) void conv_x(
    const float* __restrict__ x, unsigned short* __restrict__ xt)
{
    __shared__ __align__(16) unsigned short T[64][72];
    const int t = threadIdx.x;
    const int p0 = blockIdx.x * 64, c0 = blockIdx.y * 64, b = blockIdx.z;
    const float* xb = x + ((size_t)b * 256 + c0) * 4096 + p0;
    #pragma unroll
    for (int i = 0; i < 4; ++i) {
        int flat = i * 256 + t;
        int cl = flat >> 4, p4 = (flat & 15) * 4;
        float4 v = *(const float4*)&xb[(size_t)cl * 4096 + p4];
        T[p4 + 0][cl] = f2b(v.x);
        T[p4 + 1][cl] = f2b(v.y);
        T[p4 + 2][cl] = f2b(v.z);
        T[p4 + 3][cl] = f2b(v.w);
    }
    __syncthreads();
    unsigned short* xtb = xt + ((size_t)b * 4096 + p0) * 256 + c0;
    #pragma unroll
    for (int j = 0; j < 2; ++j) {
        int flat = j * 256 + t;
        int row = flat >> 3, ch = flat & 7;
        uint4 v = *(const uint4*)&T[row][ch * 8];
        *(uint4*)&xtb[(size_t)row * 256 + ch * 8] = v;
    }
}

// ---------------- K1: qkv[b][o][p] = sum_c Wq[o][c] * X[b][c][p], bf16 MFMA ---
__global__ __launch_bounds__(256) void qkv_mfma(
    const unsigned short* __restrict__ wq,   // [768][256] bf16
    const unsigned short* __restrict__ xt,   // [b][4096][256] bf16
    unsigned short* __restrict__ qkv)        // [b][768][4096] bf16
{
    __shared__ __align__(16) unsigned short As[128 * 64];   // 16 KB
    __shared__ __align__(16) unsigned short Bs[128 * 64];   // 16 KB
    const int t = threadIdx.x;
    const int l = t & 63, w = t >> 6;
    const int lm = l & 15, kg = l >> 4, le = l & 7, l3 = l >> 3;
    const int sx8 = (le ^ l3) * 8;          // source chunk (ushort units)
    const int p0 = blockIdx.x * 128, o0 = blockIdx.y * 128, b = blockIdx.z;
    const int wo = (w >> 1) * 64, wp = (w & 1) * 64;

    f32x4 acc[4][4] = {};
    const unsigned short* xb = xt + (size_t)b * 4096 * 256;

    for (int ks = 0; ks < 4; ++ks) {
        const int e0 = ks * 64;
        #pragma unroll
        for (int i = 0; i < 4; ++i) {
            int cid = w * 4 + i;            // 0..15, covers rows cid*8..+8
            int m = cid * 8 + l3;
            GL16(wq + (size_t)(o0 + m) * 256 + e0 + sx8, &As[cid * 512]);
            GL16(xb + (size_t)(p0 + m) * 256 + e0 + sx8, &Bs[cid * 512]);
        }
        __syncthreads();
        #pragma unroll
        for (int s = 0; s < 2; ++s) {
            bf16x8 af[4], bfr[4];
            #pragma unroll
            for (int mi = 0; mi < 4; ++mi) {
                int row = wo + mi * 16 + lm;
                int ch = ((s * 4 + kg) ^ (row & 7)) * 8;
                af[mi] = *(const bf16x8*)&As[row * 64 + ch];
            }
            #pragma unroll
            for (int ni = 0; ni < 4; ++ni) {
                int row = wp + ni * 16 + lm;
                int ch = ((s * 4 + kg) ^ (row & 7)) * 8;
                bfr[ni] = *(const bf16x8*)&Bs[row * 64 + ch];
            }
            #pragma unroll
            for (int mi = 0; mi < 4; ++mi)
                #pragma unroll
                for (int ni = 0; ni < 4; ++ni)
                    acc[mi][ni] = __builtin_amdgcn_mfma_f32_16x16x32_bf16(
                        af[mi], bfr[ni], acc[mi][ni], 0, 0, 0);
        }
        __syncthreads();
    }
    unsigned short* ob = qkv + (size_t)b * 768 * 4096;
    #pragma unroll
    for (int mi = 0; mi < 4; ++mi)
        #pragma unroll
        for (int ni = 0; ni < 4; ++ni) {
            int o = o0 + wo + mi * 16 + kg * 4;
            int p = p0 + wp + ni * 16 + lm;
            #pragma unroll
            for (int r = 0; r < 4; ++r)
                ob[(size_t)(o + r) * 4096 + p] = f2b(acc[mi][ni][r]);
        }
}

// ---------------- K2: k-softmax row stats (bf16 in) --------------------------
__global__ __launch_bounds__(256) void kstats(
    const unsigned short* __restrict__ qkv,
    float* __restrict__ kmax, float* __restrict__ krecip)
{
    const int row = blockIdx.x;              // b*256 + cd
    const int b = row >> 8, cd = row & 255;
    const int t = threadIdx.x;
    const unsigned short* kp = qkv + ((size_t)b * 768 + 256 + cd) * 4096 + t * 16;
    float v[16]; float m = -1e30f;
    u16x8 a0 = *(const u16x8*)kp;
    u16x8 a1 = *(const u16x8*)(kp + 8);
    #pragma unroll
    for (int i = 0; i < 8; ++i) { v[i] = b2f(a0[i]); v[8 + i] = b2f(a1[i]); }
    #pragma unroll
    for (int i = 0; i < 16; ++i) m = fmaxf(m, v[i]);
    #pragma unroll
    for (int off = 32; off > 0; off >>= 1) m = fmaxf(m, __shfl_xor(m, off));
    __shared__ float red[8];
    if ((t & 63) == 0) red[t >> 6] = m;
    __syncthreads();
    m = fmaxf(fmaxf(red[0], red[1]), fmaxf(red[2], red[3]));
    float s = 0.f;
    #pragma unroll
    for (int i = 0; i < 16; ++i) s += __expf(v[i] - m);
    #pragma unroll
    for (int off = 32; off > 0; off >>= 1) s += __shfl_xor(s, off);
    __syncthreads();
    if ((t & 63) == 0) red[4 + (t >> 6)] = s;
    __syncthreads();
    if (t == 0) {
        float S = red[4] + red[5] + red[6] + red[7];
        kmax[row] = m;
        krecip[row] = 1.0f / (S * 4096.0f);   // folds v/n
    }
}

// ---------------- K3: context partials (bf16 in) -----------------------------
__global__ __launch_bounds__(256) void ctx_partial(
    const unsigned short* __restrict__ qkv,
    const float* __restrict__ kmax, const float* __restrict__ krecip,
    float* __restrict__ part)
{
    const int seg = blockIdx.x, bh = blockIdx.y;
    const int b = bh >> 3, h = bh & 7;
    const int t = threadIdx.x;
    __shared__ float kc[32][65];
    __shared__ __align__(16) float vt[64][36];
    const unsigned short* kb = qkv + ((size_t)b * 768 + 256 + h * 32) * 4096;
    const unsigned short* vb = qkv + ((size_t)b * 768 + 512 + h * 32) * 4096;
    const int d = t >> 3, e0 = (t & 7) * 4;
    float a0 = 0, a1 = 0, a2 = 0, a3 = 0;

    for (int ch = 0; ch < 8; ++ch) {
        const int pb = seg * 512 + ch * 64;
        #pragma unroll
        for (int r = 0; r < 4; ++r) {
            int dd = r * 8 + (t >> 5);
            int pp = (t & 31) * 2;
            unsigned int kraw = *(const unsigned int*)&kb[(size_t)dd * 4096 + pb + pp];
            float mx = kmax[bh * 32 + dd], rc = krecip[bh * 32 + dd];
            kc[dd][pp]     = __expf(b2f((unsigned short)(kraw & 0xffff)) - mx) * rc;
            kc[dd][pp + 1] = __expf(b2f((unsigned short)(kraw >> 16)) - mx) * rc;
            unsigned int vraw = *(const unsigned int*)&vb[(size_t)dd * 4096 + pb + pp];
            vt[pp][dd]     = b2f((unsigned short)(vraw & 0xffff));
            vt[pp + 1][dd] = b2f((unsigned short)(vraw >> 16));
        }
        __syncthreads();
        #pragma unroll
        for (int pp = 0; pp < 64; ++pp) {
            float kd = kc[d][pp];
            float4 v4 = *(const float4*)&vt[pp][e0];
            a0 += kd * v4.x; a1 += kd * v4.y; a2 += kd * v4.z; a3 += kd * v4.w;
        }
        __syncthreads();
    }
    float* pp = part + ((size_t)(bh * 8 + seg) * 32 + d) * 32 + e0;
    pp[0] = a0; pp[1] = a1; pp[2] = a2; pp[3] = a3;
}

// ---------------- K3b: reduce partials -> ctxb bf16 [bh][e][d] ---------------
__global__ __launch_bounds__(256) void ctx_reduce(
    const float* __restrict__ part, unsigned short* __restrict__ ctxb)
{
    const int bh = blockIdx.x; const int t = threadIdx.x;
    #pragma unroll
    for (int r = 0; r < 4; ++r) {
        int oi = r * 256 + t;            // = e*32 + d
        int e = oi >> 5, d = oi & 31;
        float s = 0.f;
        #pragma unroll
        for (int sg = 0; sg < 8; ++sg) s += part[((size_t)bh * 8 + sg) * 1024 + d * 32 + e];
        ctxb[(size_t)bh * 1024 + oi] = f2b(s);
    }
}

// ---------------- K4: fused q-softmax + ctx + out-proj + LayerNorm -----------
// Barrier-free: all LDS wave-local. Block = 64 pixels x one batch; wave w owns
// pixels wp..wp+15. Phase A: q loaded straight into A-frag layout from global,
// softmax in-register (shfl_xor 16/32 across kg), 2 MFMA/head vs ctx (L2).
// Phase B: mfma(w_frag from global L2, out_frag from wave-local LDS) so
// C cols = pixels (lm); LN reduces in-lane + shfl_xor(16/32); direct stores.
#define RS 260
__global__ __launch_bounds__(256) void attn_out(
    const unsigned short* __restrict__ qkv,    // q part: [b][0..256][4096]
    const unsigned short* __restrict__ ctxb,   // [bh][e][d] bf16
    const unsigned short* __restrict__ woutb,  // [256 c][256 e] bf16
    const float* __restrict__ b_out, const float* __restrict__ g,
    float* __restrict__ y)
{
    __shared__ unsigned short outw[4][16][RS];   // 33,280 B, wave-private rows
    const int t = threadIdx.x, l = t & 63, w = t >> 6;
    const int lm = l & 15, kg = l >> 4;
    const int p0 = blockIdx.x * 64, b = blockIdx.y;
    const int wp = w * 16;
    const float scale = 0.17677669529663689f;   // dh^-0.5

    // ---- phase A: per-head q-softmax in A-frag + MFMA vs ctx -> outw --------
    const unsigned short* qb = qkv + (size_t)b * 768 * 4096 + p0 + wp + lm;
    #pragma unroll
    for (int h = 0; h < 8; ++h) {
        float ex[8]; float m = -1e30f;
        #pragma unroll
        for (int i = 0; i < 8; ++i) {
            ex[i] = b2f(qb[(size_t)(h * 32 + kg * 8 + i) * 4096]);
            m = fmaxf(m, ex[i]);
        }
        m = fmaxf(m, __shfl_xor(m, 16)); m = fmaxf(m, __shfl_xor(m, 32));
        float s = 0.f;
        #pragma unroll
        for (int i = 0; i < 8; ++i) { ex[i] = __expf(ex[i] - m); s += ex[i]; }
        s += __shfl_xor(s, 16); s += __shfl_xor(s, 32);
        const float inv = scale / s;
        bf16x8 a1;
        #pragma unroll
        for (int i = 0; i < 8; ++i) a1[i] = (short)f2b(ex[i] * inv);
        const unsigned short* cb = ctxb + ((size_t)(b * 8 + h)) * 1024;
        bf16x8 b1a = *(const bf16x8*)&cb[lm * 32 + kg * 8];
        bf16x8 b1b = *(const bf16x8*)&cb[(16 + lm) * 32 + kg * 8];
        f32x4 c0 = {0.f, 0.f, 0.f, 0.f}, c1 = {0.f, 0.f, 0.f, 0.f};
        c0 = __builtin_amdgcn_mfma_f32_16x16x32_bf16(a1, b1a, c0, 0, 0, 0);
        c1 = __builtin_amdgcn_mfma_f32_16x16x32_bf16(a1, b1b, c1, 0, 0, 0);
        #pragma unroll
        for (int r = 0; r < 4; ++r) {
            outw[w][kg * 4 + r][h * 32 + lm]      = f2b(c0[r]);
            outw[w][kg * 4 + r][h * 32 + 16 + lm] = f2b(c1[r]);
        }
    }

    // ---- hoist out B-fragments (wave-local LDS; hw in-order per wave) -------
    bf16x8 of[8];
    #pragma unroll
    for (int kc = 0; kc < 8; ++kc)
        of[kc] = *(const bf16x8*)&outw[w][lm][kc * 32 + kg * 8];

    // ---- phase B: C[c][p] += Wout[c][e] * out[p][e], w-frags from L2 --------
    f32x4 c2[16];
    #pragma unroll
    for (int ct = 0; ct < 16; ++ct) c2[ct] = (f32x4){0.f, 0.f, 0.f, 0.f};
    #pragma unroll
    for (int ct = 0; ct < 16; ++ct) {
        const unsigned short* wr = woutb + (size_t)(ct * 16 + lm) * 256 + kg * 8;
        #pragma unroll
        for (int kc = 0; kc < 8; ++kc) {
            bf16x8 wf = *(const bf16x8*)&wr[kc * 32];
            c2[ct] = __builtin_amdgcn_mfma_f32_16x16x32_bf16(wf, of[kc], c2[ct], 0, 0, 0);
        }
    }

    // ---- epilogue: bias + LayerNorm per pixel (col = lm) --------------------
    float s1 = 0.f, s2 = 0.f;
    #pragma unroll
    for (int ct = 0; ct < 16; ++ct) {
        float4 b4 = *(const float4*)&b_out[ct * 16 + kg * 4];
        const float bb[4] = {b4.x, b4.y, b4.z, b4.w};
        #pragma unroll
        for (int r = 0; r < 4; ++r) {
            float v = c2[ct][r] + bb[r];
            c2[ct][r] = v; s1 += v; s2 += v * v;
        }
    }
    s1 += __shfl_xor(s1, 16); s2 += __shfl_xor(s2, 16);
    s1 += __shfl_xor(s1, 32); s2 += __shfl_xor(s2, 32);
    const float mn = s1 * (1.f / 256.f);
    const float var = s2 * (1.f / 256.f) - mn * mn;
    const float rsd = rsqrtf(var + 1e-5f);

    // ---- direct stores: lanes lm = 16 consecutive pixels (64B segments) -----
    float* yb = y + (size_t)b * 256 * 4096 + p0 + wp + lm;
    #pragma unroll
    for (int ct = 0; ct < 16; ++ct) {
        float4 g4 = *(const float4*)&g[ct * 16 + kg * 4];
        const float gg[4] = {g4.x, g4.y, g4.z, g4.w};
        #pragma unroll
        for (int r = 0; r < 4; ++r)
            yb[(size_t)(ct * 16 + kg * 4 + r) * 4096] = (c2[ct][r] - mn) * rsd * gg[r];
    }
}

extern "C" void kernel_launch(void* const* d_in, const int* in_sizes, int n_in,
                              void* d_out, int out_size, void* d_ws, size_t ws_size,
                              hipStream_t stream) {
    const float* x     = (const float*)d_in[0];
    const float* w_qkv = (const float*)d_in[1];
    const float* w_out = (const float*)d_in[2];
    const float* b_out = (const float*)d_in[3];
    const float* g     = (const float*)d_in[4];
    float* y = (float*)d_out;

    char* ws = (char*)d_ws;
    unsigned short* qkvb  = (unsigned short*)ws;                    // 100,663,296
    unsigned short* xt    = (unsigned short*)(ws + 100663296);      //  33,554,432
    unsigned short* wbf   = (unsigned short*)(ws + 134217728);      //     524,288
    float*          kmax  = (float*)(ws + 134742016);               //      16,384
    float*          krec  = (float*)(ws + 134758400);               //      16,384
    float*          part  = (float*)(ws + 134774784);               //   4,194,304
    unsigned short* ctxb  = (unsigned short*)(ws + 138969088);      //     262,144

    conv_w<<<256, 256, 0, stream>>>(w_qkv, w_out, wbf);
    conv_x<<<dim3(64, 4, 16), 256, 0, stream>>>(x, xt);
    qkv_mfma<<<dim3(32, 6, 16), 256, 0, stream>>>(wbf, xt, qkvb);
    kstats<<<4096, 256, 0, stream>>>(qkvb, kmax, krec);
    ctx_partial<<<dim3(8, 128), 256, 0, stream>>>(qkvb, kmax, krec, part);
    ctx_reduce<<<128, 256, 0, stream>>>(part, ctxb);
    attn_out<<<dim3(64, 16), 256, 0, stream>>>(qkvb, ctxb, wbf + 196608, b_out, g, y);
}

// Round 6
// 331.965 us; speedup vs baseline: 1.1850x; 1.0151x over previous
//
#include <hip/hip_runtime.h>
#include <hip/hip_bf16.h>
#include <math.h>

// LinearAttention, bf16-MFMA pipeline, fused output stage (GL16-staged phase B).
// dims: B=16, C=256, H=W=64 (n=4096), HEADS=8, dh=32, HID=256, 3*HID=768.
//
// ws layout (bytes):
//   qkv_bf  @ 0          : 16*768*4096*2 = 100,663,296   (bf16)
//   xt      @ 100663296  : 16*4096*256*2 =  33,554,432   (bf16, [b][p][c])
//   wbf     @ 134217728  : (768*256 + 256*256)*2 = 524,288 (w_qkv_bf ++ w_out_bf)
//   kmax    @ 134742016  : 4096*4
//   krecip  @ 134758400  : 4096*4
//   part    @ 134774784  : 128*8*1024*4 = 4,194,304
//   ctxb    @ 138969088  : 128*1024*2   = 262,144        (bf16, [bh][e][d])

typedef __attribute__((ext_vector_type(8))) short bf16x8;
typedef __attribute__((ext_vector_type(4))) float f32x4;
typedef __attribute__((ext_vector_type(8))) unsigned short u16x8;

#define GL16(g, l) __builtin_amdgcn_global_load_lds( \
    (__attribute__((address_space(1))) void*)(void*)(g), \
    (__attribute__((address_space(3))) void*)(void*)(l), 16, 0, 0)

__device__ inline float b2f(unsigned short u) {
    union { float f; unsigned int i; } v; v.i = ((unsigned int)u) << 16; return v.f;
}
__device__ inline unsigned short f2b(float f) {
    union { float f; unsigned int i; } v; v.f = f;
    unsigned int r = v.i + 0x7fff + ((v.i >> 16) & 1);   // round-nearest-even
    return (unsigned short)(r >> 16);
}

// ---------------- K0w: weights fp32 -> bf16 (w_qkv then w_out, one arena) ----
__global__ __launch_bounds__(256) void conv_w(
    const float* __restrict__ wq, const float* __restrict__ wo,
    unsigned short* __restrict__ dst)
{
    int i4 = (blockIdx.x * 256 + threadIdx.x) * 4;   // 0..262140
    float4 v = (i4 < 196608) ? *(const float4*)&wq[i4]
                             : *(const float4*)&wo[i4 - 196608];
    unsigned int lo = (unsigned int)f2b(v.x) | ((unsigned int)f2b(v.y) << 16);
    unsigned int hi = (unsigned int)f2b(v.z) | ((unsigned int)f2b(v.w) << 16);
    *(uint2*)&dst[i4] = make_uint2(lo, hi);
}

// ---------------- K0x: x[b][c][p] fp32 -> xt[b][p][c] bf16 (tiled transpose) --
__global__ __launch_bounds__(256) void conv_x(
    const float* __restrict__ x, unsigned short* __restrict__ xt)
{
    __shared__ __align__(16) unsigned short T[64][72];
    const int t = threadIdx.x;
    const int p0 = blockIdx.x * 64, c0 = blockIdx.y * 64, b = blockIdx.z;
    const float* xb = x + ((size_t)b * 256 + c0) * 4096 + p0;
    #pragma unroll
    for (int i = 0; i < 4; ++i) {
        int flat = i * 256 + t;
        int cl = flat >> 4, p4 = (flat & 15) * 4;
        float4 v = *(const float4*)&xb[(size_t)cl * 4096 + p4];
        T[p4 + 0][cl] = f2b(v.x);
        T[p4 + 1][cl] = f2b(v.y);
        T[p4 + 2][cl] = f2b(v.z);
        T[p4 + 3][cl] = f2b(v.w);
    }
    __syncthreads();
    unsigned short* xtb = xt + ((size_t)b * 4096 + p0) * 256 + c0;
    #pragma unroll
    for (int j = 0; j < 2; ++j) {
        int flat = j * 256 + t;
        int row = flat >> 3, ch = flat & 7;
        uint4 v = *(const uint4*)&T[row][ch * 8];
        *(uint4*)&xtb[(size_t)row * 256 + ch * 8] = v;
    }
}

// ---------------- K1: qkv[b][o][p] = sum_c Wq[o][c] * X[b][c][p], bf16 MFMA ---
__global__ __launch_bounds__(256) void qkv_mfma(
    const unsigned short* __restrict__ wq,   // [768][256] bf16
    const unsigned short* __restrict__ xt,   // [b][4096][256] bf16
    unsigned short* __restrict__ qkv)        // [b][768][4096] bf16
{
    __shared__ __align__(16) unsigned short As[128 * 64];   // 16 KB
    __shared__ __align__(16) unsigned short Bs[128 * 64];   // 16 KB
    const int t = threadIdx.x;
    const int l = t & 63, w = t >> 6;
    const int lm = l & 15, kg = l >> 4, le = l & 7, l3 = l >> 3;
    const int sx8 = (le ^ l3) * 8;          // source chunk (ushort units)
    const int p0 = blockIdx.x * 128, o0 = blockIdx.y * 128, b = blockIdx.z;
    const int wo = (w >> 1) * 64, wp = (w & 1) * 64;

    f32x4 acc[4][4] = {};
    const unsigned short* xb = xt + (size_t)b * 4096 * 256;

    for (int ks = 0; ks < 4; ++ks) {
        const int e0 = ks * 64;
        #pragma unroll
        for (int i = 0; i < 4; ++i) {
            int cid = w * 4 + i;            // 0..15, covers rows cid*8..+8
            int m = cid * 8 + l3;
            GL16(wq + (size_t)(o0 + m) * 256 + e0 + sx8, &As[cid * 512]);
            GL16(xb + (size_t)(p0 + m) * 256 + e0 + sx8, &Bs[cid * 512]);
        }
        __syncthreads();
        #pragma unroll
        for (int s = 0; s < 2; ++s) {
            bf16x8 af[4], bfr[4];
            #pragma unroll
            for (int mi = 0; mi < 4; ++mi) {
                int row = wo + mi * 16 + lm;
                int ch = ((s * 4 + kg) ^ (row & 7)) * 8;
                af[mi] = *(const bf16x8*)&As[row * 64 + ch];
            }
            #pragma unroll
            for (int ni = 0; ni < 4; ++ni) {
                int row = wp + ni * 16 + lm;
                int ch = ((s * 4 + kg) ^ (row & 7)) * 8;
                bfr[ni] = *(const bf16x8*)&Bs[row * 64 + ch];
            }
            #pragma unroll
            for (int mi = 0; mi < 4; ++mi)
                #pragma unroll
                for (int ni = 0; ni < 4; ++ni)
                    acc[mi][ni] = __builtin_amdgcn_mfma_f32_16x16x32_bf16(
                        af[mi], bfr[ni], acc[mi][ni], 0, 0, 0);
        }
        __syncthreads();
    }
    unsigned short* ob = qkv + (size_t)b * 768 * 4096;
    #pragma unroll
    for (int mi = 0; mi < 4; ++mi)
        #pragma unroll
        for (int ni = 0; ni < 4; ++ni) {
            int o = o0 + wo + mi * 16 + kg * 4;
            int p = p0 + wp + ni * 16 + lm;
            #pragma unroll
            for (int r = 0; r < 4; ++r)
                ob[(size_t)(o + r) * 4096 + p] = f2b(acc[mi][ni][r]);
        }
}

// ---------------- K2: k-softmax row stats (bf16 in) --------------------------
__global__ __launch_bounds__(256) void kstats(
    const unsigned short* __restrict__ qkv,
    float* __restrict__ kmax, float* __restrict__ krecip)
{
    const int row = blockIdx.x;              // b*256 + cd
    const int b = row >> 8, cd = row & 255;
    const int t = threadIdx.x;
    const unsigned short* kp = qkv + ((size_t)b * 768 + 256 + cd) * 4096 + t * 16;
    float v[16]; float m = -1e30f;
    u16x8 a0 = *(const u16x8*)kp;
    u16x8 a1 = *(const u16x8*)(kp + 8);
    #pragma unroll
    for (int i = 0; i < 8; ++i) { v[i] = b2f(a0[i]); v[8 + i] = b2f(a1[i]); }
    #pragma unroll
    for (int i = 0; i < 16; ++i) m = fmaxf(m, v[i]);
    #pragma unroll
    for (int off = 32; off > 0; off >>= 1) m = fmaxf(m, __shfl_xor(m, off));
    __shared__ float red[8];
    if ((t & 63) == 0) red[t >> 6] = m;
    __syncthreads();
    m = fmaxf(fmaxf(red[0], red[1]), fmaxf(red[2], red[3]));
    float s = 0.f;
    #pragma unroll
    for (int i = 0; i < 16; ++i) s += __expf(v[i] - m);
    #pragma unroll
    for (int off = 32; off > 0; off >>= 1) s += __shfl_xor(s, off);
    __syncthreads();
    if ((t & 63) == 0) red[4 + (t >> 6)] = s;
    __syncthreads();
    if (t == 0) {
        float S = red[4] + red[5] + red[6] + red[7];
        kmax[row] = m;
        krecip[row] = 1.0f / (S * 4096.0f);   // folds v/n
    }
}

// ---------------- K3: context partials (bf16 in) -----------------------------
__global__ __launch_bounds__(256) void ctx_partial(
    const unsigned short* __restrict__ qkv,
    const float* __restrict__ kmax, const float* __restrict__ krecip,
    float* __restrict__ part)
{
    const int seg = blockIdx.x, bh = blockIdx.y;
    const int b = bh >> 3, h = bh & 7;
    const int t = threadIdx.x;
    __shared__ float kc[32][65];
    __shared__ __align__(16) float vt[64][36];
    const unsigned short* kb = qkv + ((size_t)b * 768 + 256 + h * 32) * 4096;
    const unsigned short* vb = qkv + ((size_t)b * 768 + 512 + h * 32) * 4096;
    const int d = t >> 3, e0 = (t & 7) * 4;
    float a0 = 0, a1 = 0, a2 = 0, a3 = 0;

    for (int ch = 0; ch < 8; ++ch) {
        const int pb = seg * 512 + ch * 64;
        #pragma unroll
        for (int r = 0; r < 4; ++r) {
            int dd = r * 8 + (t >> 5);
            int pp = (t & 31) * 2;
            unsigned int kraw = *(const unsigned int*)&kb[(size_t)dd * 4096 + pb + pp];
            float mx = kmax[bh * 32 + dd], rc = krecip[bh * 32 + dd];
            kc[dd][pp]     = __expf(b2f((unsigned short)(kraw & 0xffff)) - mx) * rc;
            kc[dd][pp + 1] = __expf(b2f((unsigned short)(kraw >> 16)) - mx) * rc;
            unsigned int vraw = *(const unsigned int*)&vb[(size_t)dd * 4096 + pb + pp];
            vt[pp][dd]     = b2f((unsigned short)(vraw & 0xffff));
            vt[pp + 1][dd] = b2f((unsigned short)(vraw >> 16));
        }
        __syncthreads();
        #pragma unroll
        for (int pp = 0; pp < 64; ++pp) {
            float kd = kc[d][pp];
            float4 v4 = *(const float4*)&vt[pp][e0];
            a0 += kd * v4.x; a1 += kd * v4.y; a2 += kd * v4.z; a3 += kd * v4.w;
        }
        __syncthreads();
    }
    float* pp = part + ((size_t)(bh * 8 + seg) * 32 + d) * 32 + e0;
    pp[0] = a0; pp[1] = a1; pp[2] = a2; pp[3] = a3;
}

// ---------------- K3b: reduce partials -> ctxb bf16 [bh][e][d] ---------------
__global__ __launch_bounds__(256) void ctx_reduce(
    const float* __restrict__ part, unsigned short* __restrict__ ctxb)
{
    const int bh = blockIdx.x; const int t = threadIdx.x;
    #pragma unroll
    for (int r = 0; r < 4; ++r) {
        int oi = r * 256 + t;            // = e*32 + d
        int e = oi >> 5, d = oi & 31;
        float s = 0.f;
        #pragma unroll
        for (int sg = 0; sg < 8; ++sg) s += part[((size_t)bh * 8 + sg) * 1024 + d * 32 + e];
        ctxb[(size_t)bh * 1024 + oi] = f2b(s);
    }
}

// ---------------- K4: fused q-softmax + ctx + out-proj + LayerNorm -----------
// Block = 64 pixels x one batch; wave w owns pixels wp..wp+15.
// Phase A: q loaded into A-frag layout from global (L3), softmax in-register
// (shfl_xor 16/32 across kg), 2 MFMA/head vs ctx (L2), out -> wave-private LDS.
// Then: hoist all 8 out B-frags to registers -> LDS becomes free -> phase B
// stages w_out k-chunks via async GL16 into the SAME LDS (union), 4 chunks x
// {bar, 8xGL16, bar, 32 MFMA}. LN in-register; direct coalesced stores.
#define RS 260
__global__ __launch_bounds__(256) void attn_out(
    const unsigned short* __restrict__ qkv,    // q part: [b][0..256][4096]
    const unsigned short* __restrict__ ctxb,   // [bh][e][d] bf16
    const unsigned short* __restrict__ woutb,  // [256 c][256 e] bf16
    const float* __restrict__ b_out, const float* __restrict__ g,
    float* __restrict__ y)
{
    __shared__ __align__(16) unsigned short smem[16640];   // 33,280 B union
    const int t = threadIdx.x, l = t & 63, w = t >> 6;
    const int lm = l & 15, kg = l >> 4, le = l & 7, l3 = l >> 3;
    const int sx8 = (le ^ l3) * 8;             // pre-swizzled source chunk
    const int p0 = blockIdx.x * 64, b = blockIdx.y;
    const int wp = w * 16;
    const float scale = 0.17677669529663689f;  // dh^-0.5

    unsigned short* outw = smem + w * (16 * RS);   // wave-private [16][RS]

    // ---- phase A: per-head q-softmax in A-frag + MFMA vs ctx -> outw --------
    const unsigned short* qb = qkv + (size_t)b * 768 * 4096 + p0 + wp + lm;
    #pragma unroll
    for (int h = 0; h < 8; ++h) {
        float ex[8]; float m = -1e30f;
        #pragma unroll
        for (int i = 0; i < 8; ++i) {
            ex[i] = b2f(qb[(size_t)(h * 32 + kg * 8 + i) * 4096]);
            m = fmaxf(m, ex[i]);
        }
        m = fmaxf(m, __shfl_xor(m, 16)); m = fmaxf(m, __shfl_xor(m, 32));
        float s = 0.f;
        #pragma unroll
        for (int i = 0; i < 8; ++i) { ex[i] = __expf(ex[i] - m); s += ex[i]; }
        s += __shfl_xor(s, 16); s += __shfl_xor(s, 32);
        const float inv = scale / s;
        bf16x8 a1;
        #pragma unroll
        for (int i = 0; i < 8; ++i) a1[i] = (short)f2b(ex[i] * inv);
        const unsigned short* cb = ctxb + ((size_t)(b * 8 + h)) * 1024;
        bf16x8 b1a = *(const bf16x8*)&cb[lm * 32 + kg * 8];
        bf16x8 b1b = *(const bf16x8*)&cb[(16 + lm) * 32 + kg * 8];
        f32x4 c0 = {0.f, 0.f, 0.f, 0.f}, c1 = {0.f, 0.f, 0.f, 0.f};
        c0 = __builtin_amdgcn_mfma_f32_16x16x32_bf16(a1, b1a, c0, 0, 0, 0);
        c1 = __builtin_amdgcn_mfma_f32_16x16x32_bf16(a1, b1b, c1, 0, 0, 0);
        #pragma unroll
        for (int r = 0; r < 4; ++r) {
            outw[(kg * 4 + r) * RS + h * 32 + lm]      = f2b(c0[r]);
            outw[(kg * 4 + r) * RS + h * 32 + 16 + lm] = f2b(c1[r]);
        }
    }

    // ---- hoist all out B-fragments (wave-local LDS, hw in-order per wave) ---
    bf16x8 of[8];
    #pragma unroll
    for (int kc = 0; kc < 8; ++kc)
        of[kc] = *(const bf16x8*)&outw[lm * RS + kc * 32 + kg * 8];

    // ---- phase B: C[c][p] += Wout[c][e] * out[p][e], GL16-staged w chunks ---
    f32x4 c2[16];
    #pragma unroll
    for (int ct = 0; ct < 16; ++ct) c2[ct] = (f32x4){0.f, 0.f, 0.f, 0.f};
    for (int ks = 0; ks < 4; ++ks) {
        __syncthreads();   // ks=0: outw reads done; ks>0: prev af reads done
        #pragma unroll
        for (int i = 0; i < 8; ++i) {
            int cid = w * 8 + i;             // 0..31, covers c rows cid*8..+8
            GL16(woutb + (size_t)(cid * 8 + l3) * 256 + ks * 64 + sx8,
                 &smem[cid * 512]);
        }
        __syncthreads();
        #pragma unroll
        for (int ct = 0; ct < 16; ++ct) {
            const int row = ct * 16 + lm;
            #pragma unroll
            for (int kc = 0; kc < 2; ++kc) {
                const int ch = ((kc * 4 + kg) ^ (row & 7)) * 8;
                bf16x8 af = *(const bf16x8*)&smem[row * 64 + ch];
                c2[ct] = __builtin_amdgcn_mfma_f32_16x16x32_bf16(
                    af, of[ks * 2 + kc], c2[ct], 0, 0, 0);
            }
        }
    }

    // ---- epilogue: bias + LayerNorm per pixel (col = lm) --------------------
    float s1 = 0.f, s2 = 0.f;
    #pragma unroll
    for (int ct = 0; ct < 16; ++ct) {
        float4 b4 = *(const float4*)&b_out[ct * 16 + kg * 4];
        const float bb[4] = {b4.x, b4.y, b4.z, b4.w};
        #pragma unroll
        for (int r = 0; r < 4; ++r) {
            float v = c2[ct][r] + bb[r];
            c2[ct][r] = v; s1 += v; s2 += v * v;
        }
    }
    s1 += __shfl_xor(s1, 16); s2 += __shfl_xor(s2, 16);
    s1 += __shfl_xor(s1, 32); s2 += __shfl_xor(s2, 32);
    const float mn = s1 * (1.f / 256.f);
    const float var = s2 * (1.f / 256.f) - mn * mn;
    const float rsd = rsqrtf(var + 1e-5f);

    // ---- direct stores: lanes lm = 16 consecutive pixels (64B segments) -----
    float* yb = y + (size_t)b * 256 * 4096 + p0 + wp + lm;
    #pragma unroll
    for (int ct = 0; ct < 16; ++ct) {
        float4 g4 = *(const float4*)&g[ct * 16 + kg * 4];
        const float gg[4] = {g4.x, g4.y, g4.z, g4.w};
        #pragma unroll
        for (int r = 0; r < 4; ++r)
            yb[(size_t)(ct * 16 + kg * 4 + r) * 4096] = (c2[ct][r] - mn) * rsd * gg[r];
    }
}

extern "C" void kernel_launch(void* const* d_in, const int* in_sizes, int n_in,
                              void* d_out, int out_size, void* d_ws, size_t ws_size,
                              hipStream_t stream) {
    const float* x     = (const float*)d_in[0];
    const float* w_qkv = (const float*)d_in[1];
    const float* w_out = (const float*)d_in[2];
    const float* b_out = (const float*)d_in[3];
    const float* g     = (const float*)d_in[4];
    float* y = (float*)d_out;

    char* ws = (char*)d_ws;
    unsigned short* qkvb  = (unsigned short*)ws;                    // 100,663,296
    unsigned short* xt    = (unsigned short*)(ws + 100663296);      //  33,554,432
    unsigned short* wbf   = (unsigned short*)(ws + 134217728);      //     524,288
    float*          kmax  = (float*)(ws + 134742016);               //      16,384
    float*          krec  = (float*)(ws + 134758400);               //      16,384
    float*          part  = (float*)(ws + 134774784);               //   4,194,304
    unsigned short* ctxb  = (unsigned short*)(ws + 138969088);      //     262,144

    conv_w<<<256, 256, 0, stream>>>(w_qkv, w_out, wbf);
    conv_x<<<dim3(64, 4, 16), 256, 0, stream>>>(x, xt);
    qkv_mfma<<<dim3(32, 6, 16), 256, 0, stream>>>(wbf, xt, qkvb);
    kstats<<<4096, 256, 0, stream>>>(qkvb, kmax, krec);
    ctx_partial<<<dim3(8, 128), 256, 0, stream>>>(qkvb, kmax, krec, part);
    ctx_reduce<<<128, 256, 0, stream>>>(part, ctxb);
    attn_out<<<dim3(64, 16), 256, 0, stream>>>(qkvb, ctxb, wbf + 196608, b_out, g, y);
}

// Round 7
// 255.240 us; speedup vs baseline: 1.5412x; 1.3006x over previous
//
#include <hip/hip_runtime.h>
#include <hip/hip_bf16.h>
#include <math.h>

// LinearAttention, bf16-MFMA pipeline, split output stage (qctx2 + proj_ln).
// dims: B=16, C=256, H=W=64 (n=4096), HEADS=8, dh=32, HID=256, 3*HID=768.
//
// ws layout (bytes):
//   qkv_bf  @ 0          : 16*768*4096*2 = 100,663,296   (bf16)
//   xt      @ 100663296  : 16*4096*256*2 =  33,554,432   (bf16, [b][p][c])
//   wbf     @ 134217728  : (768*256 + 256*256)*2 = 524,288 (w_qkv_bf ++ w_out_bf)
//   kmax    @ 134742016  : 4096*4
//   krecip  @ 134758400  : 4096*4
//   part    @ 134774784  : 128*8*1024*4 = 4,194,304
//   ctxb    @ 138969088  : 128*1024*2   = 262,144        (bf16, [bh][e][d])
//   outt    @ 139231232  : 16*4096*256*2 = 33,554,432    (bf16, [b][p][e])
//   total ~173 MB

typedef __attribute__((ext_vector_type(8))) short bf16x8;
typedef __attribute__((ext_vector_type(4))) float f32x4;
typedef __attribute__((ext_vector_type(8))) unsigned short u16x8;

#define GL16(g, l) __builtin_amdgcn_global_load_lds( \
    (__attribute__((address_space(1))) void*)(void*)(g), \
    (__attribute__((address_space(3))) void*)(void*)(l), 16, 0, 0)

__device__ inline float b2f(unsigned short u) {
    union { float f; unsigned int i; } v; v.i = ((unsigned int)u) << 16; return v.f;
}
__device__ inline unsigned short f2b(float f) {
    union { float f; unsigned int i; } v; v.f = f;
    unsigned int r = v.i + 0x7fff + ((v.i >> 16) & 1);   // round-nearest-even
    return (unsigned short)(r >> 16);
}

// ---------------- K0w: weights fp32 -> bf16 (w_qkv then w_out, one arena) ----
__global__ __launch_bounds__(256) void conv_w(
    const float* __restrict__ wq, const float* __restrict__ wo,
    unsigned short* __restrict__ dst)
{
    int i4 = (blockIdx.x * 256 + threadIdx.x) * 4;   // 0..262140
    float4 v = (i4 < 196608) ? *(const float4*)&wq[i4]
                             : *(const float4*)&wo[i4 - 196608];
    unsigned int lo = (unsigned int)f2b(v.x) | ((unsigned int)f2b(v.y) << 16);
    unsigned int hi = (unsigned int)f2b(v.z) | ((unsigned int)f2b(v.w) << 16);
    *(uint2*)&dst[i4] = make_uint2(lo, hi);
}

// ---------------- K0x: x[b][c][p] fp32 -> xt[b][p][c] bf16 (tiled transpose) --
__global__ __launch_bounds__(256) void conv_x(
    const float* __restrict__ x, unsigned short* __restrict__ xt)
{
    __shared__ __align__(16) unsigned short T[64][72];
    const int t = threadIdx.x;
    const int p0 = blockIdx.x * 64, c0 = blockIdx.y * 64, b = blockIdx.z;
    const float* xb = x + ((size_t)b * 256 + c0) * 4096 + p0;
    #pragma unroll
    for (int i = 0; i < 4; ++i) {
        int flat = i * 256 + t;
        int cl = flat >> 4, p4 = (flat & 15) * 4;
        float4 v = *(const float4*)&xb[(size_t)cl * 4096 + p4];
        T[p4 + 0][cl] = f2b(v.x);
        T[p4 + 1][cl] = f2b(v.y);
        T[p4 + 2][cl] = f2b(v.z);
        T[p4 + 3][cl] = f2b(v.w);
    }
    __syncthreads();
    unsigned short* xtb = xt + ((size_t)b * 4096 + p0) * 256 + c0;
    #pragma unroll
    for (int j = 0; j < 2; ++j) {
        int flat = j * 256 + t;
        int row = flat >> 3, ch = flat & 7;
        uint4 v = *(const uint4*)&T[row][ch * 8];
        *(uint4*)&xtb[(size_t)row * 256 + ch * 8] = v;
    }
}

// ---------------- K1: qkv[b][o][p] = sum_c Wq[o][c] * X[b][c][p], bf16 MFMA ---
__global__ __launch_bounds__(256) void qkv_mfma(
    const unsigned short* __restrict__ wq,   // [768][256] bf16
    const unsigned short* __restrict__ xt,   // [b][4096][256] bf16
    unsigned short* __restrict__ qkv)        // [b][768][4096] bf16
{
    __shared__ __align__(16) unsigned short As[128 * 64];   // 16 KB
    __shared__ __align__(16) unsigned short Bs[128 * 64];   // 16 KB
    const int t = threadIdx.x;
    const int l = t & 63, w = t >> 6;
    const int lm = l & 15, kg = l >> 4, le = l & 7, l3 = l >> 3;
    const int sx8 = (le ^ l3) * 8;          // source chunk (ushort units)
    const int p0 = blockIdx.x * 128, o0 = blockIdx.y * 128, b = blockIdx.z;
    const int wo = (w >> 1) * 64, wp = (w & 1) * 64;

    f32x4 acc[4][4] = {};
    const unsigned short* xb = xt + (size_t)b * 4096 * 256;

    for (int ks = 0; ks < 4; ++ks) {
        const int e0 = ks * 64;
        #pragma unroll
        for (int i = 0; i < 4; ++i) {
            int cid = w * 4 + i;            // 0..15, covers rows cid*8..+8
            int m = cid * 8 + l3;
            GL16(wq + (size_t)(o0 + m) * 256 + e0 + sx8, &As[cid * 512]);
            GL16(xb + (size_t)(p0 + m) * 256 + e0 + sx8, &Bs[cid * 512]);
        }
        __syncthreads();
        #pragma unroll
        for (int s = 0; s < 2; ++s) {
            bf16x8 af[4], bfr[4];
            #pragma unroll
            for (int mi = 0; mi < 4; ++mi) {
                int row = wo + mi * 16 + lm;
                int ch = ((s * 4 + kg) ^ (row & 7)) * 8;
                af[mi] = *(const bf16x8*)&As[row * 64 + ch];
            }
            #pragma unroll
            for (int ni = 0; ni < 4; ++ni) {
                int row = wp + ni * 16 + lm;
                int ch = ((s * 4 + kg) ^ (row & 7)) * 8;
                bfr[ni] = *(const bf16x8*)&Bs[row * 64 + ch];
            }
            #pragma unroll
            for (int mi = 0; mi < 4; ++mi)
                #pragma unroll
                for (int ni = 0; ni < 4; ++ni)
                    acc[mi][ni] = __builtin_amdgcn_mfma_f32_16x16x32_bf16(
                        af[mi], bfr[ni], acc[mi][ni], 0, 0, 0);
        }
        __syncthreads();
    }
    unsigned short* ob = qkv + (size_t)b * 768 * 4096;
    #pragma unroll
    for (int mi = 0; mi < 4; ++mi)
        #pragma unroll
        for (int ni = 0; ni < 4; ++ni) {
            int o = o0 + wo + mi * 16 + kg * 4;
            int p = p0 + wp + ni * 16 + lm;
            #pragma unroll
            for (int r = 0; r < 4; ++r)
                ob[(size_t)(o + r) * 4096 + p] = f2b(acc[mi][ni][r]);
        }
}

// ---------------- K2: k-softmax row stats (bf16 in) --------------------------
__global__ __launch_bounds__(256) void kstats(
    const unsigned short* __restrict__ qkv,
    float* __restrict__ kmax, float* __restrict__ krecip)
{
    const int row = blockIdx.x;              // b*256 + cd
    const int b = row >> 8, cd = row & 255;
    const int t = threadIdx.x;
    const unsigned short* kp = qkv + ((size_t)b * 768 + 256 + cd) * 4096 + t * 16;
    float v[16]; float m = -1e30f;
    u16x8 a0 = *(const u16x8*)kp;
    u16x8 a1 = *(const u16x8*)(kp + 8);
    #pragma unroll
    for (int i = 0; i < 8; ++i) { v[i] = b2f(a0[i]); v[8 + i] = b2f(a1[i]); }
    #pragma unroll
    for (int i = 0; i < 16; ++i) m = fmaxf(m, v[i]);
    #pragma unroll
    for (int off = 32; off > 0; off >>= 1) m = fmaxf(m, __shfl_xor(m, off));
    __shared__ float red[8];
    if ((t & 63) == 0) red[t >> 6] = m;
    __syncthreads();
    m = fmaxf(fmaxf(red[0], red[1]), fmaxf(red[2], red[3]));
    float s = 0.f;
    #pragma unroll
    for (int i = 0; i < 16; ++i) s += __expf(v[i] - m);
    #pragma unroll
    for (int off = 32; off > 0; off >>= 1) s += __shfl_xor(s, off);
    __syncthreads();
    if ((t & 63) == 0) red[4 + (t >> 6)] = s;
    __syncthreads();
    if (t == 0) {
        float S = red[4] + red[5] + red[6] + red[7];
        kmax[row] = m;
        krecip[row] = 1.0f / (S * 4096.0f);   // folds v/n
    }
}

// ---------------- K3: context partials (bf16 in) -----------------------------
__global__ __launch_bounds__(256) void ctx_partial(
    const unsigned short* __restrict__ qkv,
    const float* __restrict__ kmax, const float* __restrict__ krecip,
    float* __restrict__ part)
{
    const int seg = blockIdx.x, bh = blockIdx.y;
    const int b = bh >> 3, h = bh & 7;
    const int t = threadIdx.x;
    __shared__ float kc[32][65];
    __shared__ __align__(16) float vt[64][36];
    const unsigned short* kb = qkv + ((size_t)b * 768 + 256 + h * 32) * 4096;
    const unsigned short* vb = qkv + ((size_t)b * 768 + 512 + h * 32) * 4096;
    const int d = t >> 3, e0 = (t & 7) * 4;
    float a0 = 0, a1 = 0, a2 = 0, a3 = 0;

    for (int ch = 0; ch < 8; ++ch) {
        const int pb = seg * 512 + ch * 64;
        #pragma unroll
        for (int r = 0; r < 4; ++r) {
            int dd = r * 8 + (t >> 5);
            int pp = (t & 31) * 2;
            unsigned int kraw = *(const unsigned int*)&kb[(size_t)dd * 4096 + pb + pp];
            float mx = kmax[bh * 32 + dd], rc = krecip[bh * 32 + dd];
            kc[dd][pp]     = __expf(b2f((unsigned short)(kraw & 0xffff)) - mx) * rc;
            kc[dd][pp + 1] = __expf(b2f((unsigned short)(kraw >> 16)) - mx) * rc;
            unsigned int vraw = *(const unsigned int*)&vb[(size_t)dd * 4096 + pb + pp];
            vt[pp][dd]     = b2f((unsigned short)(vraw & 0xffff));
            vt[pp + 1][dd] = b2f((unsigned short)(vraw >> 16));
        }
        __syncthreads();
        #pragma unroll
        for (int pp = 0; pp < 64; ++pp) {
            float kd = kc[d][pp];
            float4 v4 = *(const float4*)&vt[pp][e0];
            a0 += kd * v4.x; a1 += kd * v4.y; a2 += kd * v4.z; a3 += kd * v4.w;
        }
        __syncthreads();
    }
    float* pp = part + ((size_t)(bh * 8 + seg) * 32 + d) * 32 + e0;
    pp[0] = a0; pp[1] = a1; pp[2] = a2; pp[3] = a3;
}

// ---------------- K3b: reduce partials -> ctxb bf16 [bh][e][d] ---------------
__global__ __launch_bounds__(256) void ctx_reduce(
    const float* __restrict__ part, unsigned short* __restrict__ ctxb)
{
    const int bh = blockIdx.x; const int t = threadIdx.x;
    #pragma unroll
    for (int r = 0; r < 4; ++r) {
        int oi = r * 256 + t;            // = e*32 + d
        int e = oi >> 5, d = oi & 31;
        float s = 0.f;
        #pragma unroll
        for (int sg = 0; sg < 8; ++sg) s += part[((size_t)bh * 8 + sg) * 1024 + d * 32 + e];
        ctxb[(size_t)bh * 1024 + oi] = f2b(s);
    }
}

// ---------------- K4a: q-softmax (A-frag) + ctx MFMA -> outt[b][p][e] --------
// Barrier-free. Block = 64 pixels x one batch; wave w owns pixels wp..wp+15.
// Per head: 8 scalar q loads/lane into A-frag layout, softmax in-register
// (shfl_xor 16/32 across kg), 2 MFMA vs ctxb (L2), result -> wave-private LDS.
// Writeout: 8 coalesced u16x8 passes (wave-local LDS, no __syncthreads).
#define RS 260
__global__ __launch_bounds__(256) void qctx2(
    const unsigned short* __restrict__ qkv,    // q part: [b][0..256][4096]
    const unsigned short* __restrict__ ctxb,   // [bh][e][d] bf16
    unsigned short* __restrict__ outt)         // [b][p][e] bf16
{
    __shared__ unsigned short outw[4][16][RS];   // 33,280 B, wave-private rows
    const int t = threadIdx.x, l = t & 63, w = t >> 6;
    const int lm = l & 15, kg = l >> 4;
    const int p0 = blockIdx.x * 64, b = blockIdx.y;
    const int wp = w * 16;
    const float scale = 0.17677669529663689f;   // dh^-0.5

    const unsigned short* qb = qkv + (size_t)b * 768 * 4096 + p0 + wp + lm;
    #pragma unroll
    for (int h = 0; h < 8; ++h) {
        float ex[8]; float m = -1e30f;
        #pragma unroll
        for (int i = 0; i < 8; ++i) {
            ex[i] = b2f(qb[(size_t)(h * 32 + kg * 8 + i) * 4096]);
            m = fmaxf(m, ex[i]);
        }
        m = fmaxf(m, __shfl_xor(m, 16)); m = fmaxf(m, __shfl_xor(m, 32));
        float s = 0.f;
        #pragma unroll
        for (int i = 0; i < 8; ++i) { ex[i] = __expf(ex[i] - m); s += ex[i]; }
        s += __shfl_xor(s, 16); s += __shfl_xor(s, 32);
        const float inv = scale / s;
        bf16x8 a1;
        #pragma unroll
        for (int i = 0; i < 8; ++i) a1[i] = (short)f2b(ex[i] * inv);
        const unsigned short* cb = ctxb + ((size_t)(b * 8 + h)) * 1024;
        bf16x8 b1a = *(const bf16x8*)&cb[lm * 32 + kg * 8];
        bf16x8 b1b = *(const bf16x8*)&cb[(16 + lm) * 32 + kg * 8];
        f32x4 c0 = {0.f, 0.f, 0.f, 0.f}, c1 = {0.f, 0.f, 0.f, 0.f};
        c0 = __builtin_amdgcn_mfma_f32_16x16x32_bf16(a1, b1a, c0, 0, 0, 0);
        c1 = __builtin_amdgcn_mfma_f32_16x16x32_bf16(a1, b1b, c1, 0, 0, 0);
        #pragma unroll
        for (int r = 0; r < 4; ++r) {
            outw[w][kg * 4 + r][h * 32 + lm]      = f2b(c0[r]);
            outw[w][kg * 4 + r][h * 32 + 16 + lm] = f2b(c1[r]);
        }
    }

    // coalesced writeout: wave w stores its 16 rows (16x256 e), 1 KB per pass
    unsigned short* ob = outt + ((size_t)(b * 4096 + p0 + wp)) * 256;
    #pragma unroll
    for (int pass = 0; pass < 8; ++pass) {
        int row = l >> 2, ec = (l & 3) * 8 + pass * 32;
        u16x8 v = *(const u16x8*)&outw[w][row][ec];
        *(u16x8*)&ob[(size_t)row * 256 + ec] = v;
    }
}

// ---------------- K4b: y = Wout*out + b_out, fused LayerNorm, MFMA -----------
// BM=256 (all c in-block -> LN fuses), BN=64 p, BK=64, 4 waves.
__global__ __launch_bounds__(256) void proj_ln(
    const unsigned short* __restrict__ woutb,   // [256][256] bf16
    const unsigned short* __restrict__ outt,    // [b][4096][256] bf16
    const float* __restrict__ b_out, const float* __restrict__ g,
    float* __restrict__ y)
{
    __shared__ __align__(16) unsigned short As[256 * 64];   // 32 KB
    __shared__ __align__(16) unsigned short Bs[64 * 64];    // 8 KB
    __shared__ float red1[4][64], red2[4][64], mean_s[64], rstd_s[64];
    const int t = threadIdx.x;
    const int l = t & 63, w = t >> 6;
    const int lm = l & 15, kg = l >> 4, le = l & 7, l3 = l >> 3;
    const int sx8 = (le ^ l3) * 8;
    const int pb = blockIdx.x * 64, b = blockIdx.y;

    f32x4 acc[4][4] = {};
    const unsigned short* outb = outt + (size_t)b * 4096 * 256;

    for (int ks = 0; ks < 4; ++ks) {
        const int e0 = ks * 64;
        #pragma unroll
        for (int i = 0; i < 8; ++i) {
            int cid = w * 8 + i;                 // 0..31
            int m = cid * 8 + l3;                // c row 0..255
            GL16(woutb + (size_t)m * 256 + e0 + sx8, &As[cid * 512]);
        }
        #pragma unroll
        for (int i = 0; i < 2; ++i) {
            int cid = w * 2 + i;                 // 0..7
            int m = cid * 8 + l3;                // p row 0..63
            GL16(outb + (size_t)(pb + m) * 256 + e0 + sx8, &Bs[cid * 512]);
        }
        __syncthreads();
        #pragma unroll
        for (int s = 0; s < 2; ++s) {
            bf16x8 af[4], bfr[4];
            #pragma unroll
            for (int mi = 0; mi < 4; ++mi) {
                int row = w * 64 + mi * 16 + lm;
                int ch = ((s * 4 + kg) ^ (row & 7)) * 8;
                af[mi] = *(const bf16x8*)&As[row * 64 + ch];
            }
            #pragma unroll
            for (int ni = 0; ni < 4; ++ni) {
                int row = ni * 16 + lm;
                int ch = ((s * 4 + kg) ^ (row & 7)) * 8;
                bfr[ni] = *(const bf16x8*)&Bs[row * 64 + ch];
            }
            #pragma unroll
            for (int mi = 0; mi < 4; ++mi)
                #pragma unroll
                for (int ni = 0; ni < 4; ++ni)
                    acc[mi][ni] = __builtin_amdgcn_mfma_f32_16x16x32_bf16(
                        af[mi], bfr[ni], acc[mi][ni], 0, 0, 0);
        }
        __syncthreads();
    }
    // bias + gamma (c = w*64 + mi*16 + kg*4 + r)
    float bo[4][4], gv[4][4];
    #pragma unroll
    for (int mi = 0; mi < 4; ++mi)
        #pragma unroll
        for (int r = 0; r < 4; ++r) {
            int c = w * 64 + mi * 16 + kg * 4 + r;
            bo[mi][r] = b_out[c]; gv[mi][r] = g[c];
        }
    #pragma unroll
    for (int mi = 0; mi < 4; ++mi)
        #pragma unroll
        for (int ni = 0; ni < 4; ++ni)
            #pragma unroll
            for (int r = 0; r < 4; ++r)
                acc[mi][ni][r] += bo[mi][r];
    // LN stats: per p (col), sum over 256 c
    #pragma unroll
    for (int ni = 0; ni < 4; ++ni) {
        float s1 = 0.f, s2 = 0.f;
        #pragma unroll
        for (int mi = 0; mi < 4; ++mi)
            #pragma unroll
            for (int r = 0; r < 4; ++r) { float v = acc[mi][ni][r]; s1 += v; s2 += v * v; }
        s1 += __shfl_xor(s1, 16); s2 += __shfl_xor(s2, 16);
        s1 += __shfl_xor(s1, 32); s2 += __shfl_xor(s2, 32);
        if (kg == 0) { red1[w][ni * 16 + lm] = s1; red2[w][ni * 16 + lm] = s2; }
    }
    __syncthreads();
    if (t < 64) {
        float s1 = red1[0][t] + red1[1][t] + red1[2][t] + red1[3][t];
        float s2 = red2[0][t] + red2[1][t] + red2[2][t] + red2[3][t];
        float mn = s1 * (1.f / 256.f);
        float var = s2 * (1.f / 256.f) - mn * mn;
        mean_s[t] = mn; rstd_s[t] = rsqrtf(var + 1e-5f);
    }
    __syncthreads();
    float* yb = y + (size_t)b * 256 * 4096 + pb;
    #pragma unroll
    for (int ni = 0; ni < 4; ++ni) {
        int p = ni * 16 + lm;
        float mn = mean_s[p], rs = rstd_s[p];
        #pragma unroll
        for (int mi = 0; mi < 4; ++mi) {
            int c = w * 64 + mi * 16 + kg * 4;
            #pragma unroll
            for (int r = 0; r < 4; ++r)
                yb[(size_t)(c + r) * 4096 + p] = (acc[mi][ni][r] - mn) * rs * gv[mi][r];
        }
    }
}

extern "C" void kernel_launch(void* const* d_in, const int* in_sizes, int n_in,
                              void* d_out, int out_size, void* d_ws, size_t ws_size,
                              hipStream_t stream) {
    const float* x     = (const float*)d_in[0];
    const float* w_qkv = (const float*)d_in[1];
    const float* w_out = (const float*)d_in[2];
    const float* b_out = (const float*)d_in[3];
    const float* g     = (const float*)d_in[4];
    float* y = (float*)d_out;

    char* ws = (char*)d_ws;
    unsigned short* qkvb  = (unsigned short*)ws;                    // 100,663,296
    unsigned short* xt    = (unsigned short*)(ws + 100663296);      //  33,554,432
    unsigned short* wbf   = (unsigned short*)(ws + 134217728);      //     524,288
    float*          kmax  = (float*)(ws + 134742016);               //      16,384
    float*          krec  = (float*)(ws + 134758400);               //      16,384
    float*          part  = (float*)(ws + 134774784);               //   4,194,304
    unsigned short* ctxb  = (unsigned short*)(ws + 138969088);      //     262,144
    unsigned short* outt  = (unsigned short*)(ws + 139231232);      //  33,554,432

    conv_w<<<256, 256, 0, stream>>>(w_qkv, w_out, wbf);
    conv_x<<<dim3(64, 4, 16), 256, 0, stream>>>(x, xt);
    qkv_mfma<<<dim3(32, 6, 16), 256, 0, stream>>>(wbf, xt, qkvb);
    kstats<<<4096, 256, 0, stream>>>(qkvb, kmax, krec);
    ctx_partial<<<dim3(8, 128), 256, 0, stream>>>(qkvb, kmax, krec, part);
    ctx_reduce<<<128, 256, 0, stream>>>(part, ctxb);
    qctx2<<<dim3(64, 16), 256, 0, stream>>>(qkvb, ctxb, outt);
    proj_ln<<<dim3(64, 16), 256, 0, stream>>>(wbf + 196608, outt, b_out, g, y);
}